// Round 3
// baseline (163.334 us; speedup 1.0000x reference)
//
#include <hip/hip_runtime.h>

// Problem constants from the reference
#define BB 64
#define VV 8
#define JJ 17
#define HH 256
#define NN (BB * VV * JJ)     // 8704 gathered elements total
#define NBLK (NN / 64)        // 136 blocks of one wave each (exact)

// One element per thread, 136 blocks x 64 threads spread across CUs so all
// 8704 scattered gathers issue in one HBM-latency round. Each wave
// shuffle-reduces its 64 values and atomically accumulates the pre-scaled
// partial into out[0] (zeroed by a memset node before this kernel).
__global__ __launch_bounds__(64) void HeatmapCELoss_gather(
    const float* __restrict__ kp,   // (B, V, J, 2) float32
    const float* __restrict__ hm,   // (B, V, 1, H, H) float32
    float* __restrict__ out)        // scalar accumulator (pre-zeroed)
{
    const int i = blockIdx.x * 64 + threadIdx.x;   // i in [0, 8704)

    // keypoints are (x, y) pairs, contiguous -> coalesced float2 load
    float2 k = ((const float2*)kp)[i];
    int x = (int)ceilf(k.x);
    int y = (int)ceilf(k.y);
    x = min(max(x, 0), HH - 1);
    y = min(max(y, 0), HH - 1);
    int bv = i / JJ;   // (b,v) plane index; compiler emits magic-mul for /17

    float val = hm[((size_t)bv * HH + (size_t)y) * HH + (size_t)x];
    float s = -__logf(val);

    // 64-lane wave shuffle reduction
    #pragma unroll
    for (int off = 32; off > 0; off >>= 1)
        s += __shfl_down(s, off, 64);

    // One device-scope fp32 atomic per block (136 total, negligible contention)
    if (threadIdx.x == 0) atomicAdd(out, s * (1.0f / (float)NN));
}

extern "C" void kernel_launch(void* const* d_in, const int* in_sizes, int n_in,
                              void* d_out, int out_size, void* d_ws, size_t ws_size,
                              hipStream_t stream) {
    const float* kp = (const float*)d_in[0];  // keypoints_gt (64,8,17,2) f32
    const float* hm = (const float*)d_in[1];  // heatmap (64,8,1,256,256) f32
    float* out = (float*)d_out;

    // Zero the scalar accumulator (graph memset node, off the critical path
    // relative to the gather latency), then accumulate atomically.
    hipMemsetAsync(out, 0, sizeof(float), stream);
    HeatmapCELoss_gather<<<NBLK, 64, 0, stream>>>(kp, hm, out);
}